// Round 1
// baseline (4614.341 us; speedup 1.0000x reference)
//
#include <hip/hip_runtime.h>
#include <cstdint>
#include <cmath>

#define T_STEPS 1460
#define N_GRID  2000
#define UH_LEN  15
#define NZ      1e-6f

// sigmoid-bounded parameter transform (matches ref: lo + sigmoid(x)*(hi-lo))
__device__ __forceinline__ float pb(float x, float lo, float hi) {
    float s = 1.0f / (1.0f + expf(-x));
    return lo + s * (hi - lo);
}

__device__ __forceinline__ float clip01(float x) {
    return fminf(fmaxf(x, NZ), 1.0f);
}

// gate = round(sigmoid(x)) with round-half-to-even.
// For |x| > 1e-4 this is exactly (x > 0).  In the tiny window near 0 use
// double precision sigmoid + rint (banker's rounding) to track the reference.
__device__ __forceinline__ float gatef(float x) {
    if (fabsf(x) < 1e-4f) {
        double s = 1.0 / (1.0 + exp(-(double)x));
        return (float)rint(s);
    }
    return (x > 0.0f) ? 1.0f : 0.0f;
}

// ---------------------------------------------------------------------------
// Kernel 1: per-cell unit hydrograph weights (softmax over 15 lags, 2 sets)
// layout: uh[lag * N_GRID + g]  (coalesced reads in routing kernel)
// ---------------------------------------------------------------------------
__global__ __launch_bounds__(256)
void uh_kernel(const float* __restrict__ hyb,
               float* __restrict__ uh1, float* __restrict__ uh2)
{
    const int g = blockIdx.x * 256 + threadIdx.x;
    if (g >= N_GRID) return;
    const float* h = hyb + (size_t)g * 32;
    const float a1 = pb(h[28], 0.3f, 20.0f);
    const float b1 = pb(h[29], 0.01f, 5.0f);
    const float a2 = pb(h[30], 0.5f, 13.0f);
    const float b2 = pb(h[31], 0.15f, 1.5f);

    float lw[UH_LEN];
    // --- set 1 ---
    {
        float m = -1e30f;
        #pragma unroll
        for (int k = 0; k < UH_LEN; ++k) {
            const float kk = (float)(k + 1);
            lw[k] = (a1 - 1.0f) * logf(kk) - kk / b1;
            m = fmaxf(m, lw[k]);
        }
        float s = 0.0f;
        #pragma unroll
        for (int k = 0; k < UH_LEN; ++k) { lw[k] = expf(lw[k] - m); s += lw[k]; }
        const float inv = 1.0f / s;
        #pragma unroll
        for (int k = 0; k < UH_LEN; ++k) uh1[k * N_GRID + g] = lw[k] * inv;
    }
    // --- set 2 ---
    {
        float m = -1e30f;
        #pragma unroll
        for (int k = 0; k < UH_LEN; ++k) {
            const float kk = (float)(k + 1);
            lw[k] = (a2 - 1.0f) * logf(kk) - kk / b2;
            m = fmaxf(m, lw[k]);
        }
        float s = 0.0f;
        #pragma unroll
        for (int k = 0; k < UH_LEN; ++k) { lw[k] = expf(lw[k] - m); s += lw[k]; }
        const float inv = 1.0f / s;
        #pragma unroll
        for (int k = 0; k < UH_LEN; ++k) uh2[k * N_GRID + g] = lw[k] * inv;
    }
}

// ---------------------------------------------------------------------------
// Kernel 2: the sequential scan — one thread per grid cell, loop over T.
// Latency/issue-bound (2000 threads = ~32 waves); next-step inputs are
// prefetched into registers at loop top to hide HBM latency.
// ---------------------------------------------------------------------------
__global__ __launch_bounds__(64)
void scan_kernel(const float* __restrict__ xphy,   // (T, G, 3)
                 const float* __restrict__ wts,    // (T, G, 24)
                 const float* __restrict__ hyb,    // (G, 32)
                 float* __restrict__ surf_o,       // (T, G)
                 float* __restrict__ base_o,       // (T, G)
                 unsigned char* __restrict__ gate_o) // (T, G) bit0=g4 bit1=g5
{
    const int g = blockIdx.x * 64 + threadIdx.x;
    if (g >= N_GRID) return;

    const float* h = hyb + (size_t)g * 32;
    // --- bounded parameters (once per thread) ---
    const float inf_pc   = pb(h[0],  0.0f,   1.0f);
    const float hbv_beta = pb(h[1],  0.5f,   3.0f);
    const float vic_bexp = pb(h[2],  0.001f, 3.0f);
    const float hmets_al = pb(h[3],  0.3f,   1.0f);
    const float x3_1     = pb(h[4],  20.0f,  300.0f);
    const float bfc1     = pb(h[5],  -8.0f,  -2.0f);
    const float bfn1     = pb(h[6],  1.0f,   5.0f);
    const float bfmax1   = pb(h[7],  0.1f,   200.0f);
    const float lam      = pb(h[8],  0.1f,   0.5f);
    const float th1      = pb(h[9],  0.0001f,0.9999f);
    const float max_perc = pb(h[10], 1.0f,   50.0f);
    const float sfc      = pb(h[11], 0.0001f,0.9999f);
    const float crise    = pb(h[12], 0.1f,   50.0f);
    const float bfmax2   = pb(h[13], 0.1f,   100.0f);
    const float x3_2     = pb(h[14], 50.0f,  500.0f);
    const float bfc2     = pb(h[15], -8.0f,  -2.0f);
    const float bfn2     = pb(h[16], 1.0f,   5.0f);
    const float Tbf      = pb(h[17], -5.0f,  2.0f);
    const float Kf       = pb(h[18], 0.0f,   5.0f);
    const float ddf_min  = pb(h[19], 1.5f,   3.0f);
    const float ddf_plus = pb(h[20], 0.0f,   5.0f);
    const float Kcum     = pb(h[21], 0.01f,  0.2f);
    const float Tbm      = pb(h[22], -1.0f,  1.0f);
    const float swi      = pb(h[23], 0.0f,   0.4f);
    const float fc       = pb(h[24], 0.0f,   1.0f);
    const float fs       = pb(h[25], 0.0f,   1.0f);
    const float msw1     = pb(h[26], 50.0f,  500.0f);
    const float msw2     = pb(h[27], 50.0f,  500.0f);

    // --- derived per-grid constants ---
    const float inv_msw1  = 1.0f / msw1;
    const float inv_msw2  = 1.0f / msw2;
    const float canopy_fac = fc * (1.0f - fs);
    const float pow10_1   = powf(10.0f, bfc1);
    const float pow10_2   = powf(10.0f, bfc2);
    const float inv_x3_1  = 1.0f / x3_1;
    const float inv_x3_2  = 1.0f / x3_2;
    const float b1o4      = bfmax1 / expm1f(lam);
    const float b1o5      = bfmax1 / (1.0f - th1);
    const float perc_fac  = max_perc / (1.0f - sfc);

    // --- state ---
    float snow = NZ, liq = NZ, cum = NZ, sw1 = NZ, sw2 = NZ;

    // --- prefetch t=0 ---
    float4 wc0, wc1, wc2, wc3, wc4, wc5;
    float xc0, xc1, xc2;
    {
        const float* xp = xphy + (size_t)g * 3;
        xc0 = xp[0]; xc1 = xp[1]; xc2 = xp[2];
        const float4* wp = (const float4*)(wts + (size_t)g * 24);
        wc0 = wp[0]; wc1 = wp[1]; wc2 = wp[2]; wc3 = wp[3]; wc4 = wp[4]; wc5 = wp[5];
    }

    for (int t = 0; t < T_STEPS; ++t) {
        // prefetch next step's inputs (redundant reload at t = T-1, unused)
        const int tn = (t + 1 < T_STEPS) ? (t + 1) : t;
        float4 wn0, wn1, wn2, wn3, wn4, wn5;
        float xn0, xn1, xn2;
        {
            const float* xp = xphy + ((size_t)tn * N_GRID + g) * 3;
            xn0 = xp[0]; xn1 = xp[1]; xn2 = xp[2];
            const float4* wp = (const float4*)(wts + ((size_t)tn * N_GRID + g) * 24);
            wn0 = wp[0]; wn1 = wp[1]; wn2 = wp[2]; wn3 = wp[3]; wn4 = wp[4]; wn5 = wp[5];
        }

        const float prcp = xc0, temp = xc1, pet = xc2;

        // gates (channels 18..23)
        const float g0 = gatef(wc4.z);
        const float g1 = gatef(wc4.w);
        const float g2 = gatef(wc5.x);
        const float g3 = gatef(wc5.y);
        const float g4 = gatef(wc5.z);
        const float g5 = gatef(wc5.w);

        // --- snow / rain partition + canopy interception ---
        float rain  = (temp >= 0.0f) ? prcp : 0.0f;
        float snowf = (temp <  0.0f) ? prcp : 0.0f;
        const float canopy = pet * canopy_fac;
        rain  = fmaxf(rain  - canopy * g2, 0.0f);
        snowf = fmaxf(snowf - canopy * g3, 0.0f);

        const float refreeze = fminf(liq, Kf * fmaxf(Tbf - temp, 0.0f));
        snow = snow + snowf + refreeze;
        liq  = liq - refreeze;
        const float ddf = ddf_min + ddf_plus * (1.0f - __expf(-Kcum * cum));
        const float melt = fminf(snow, ddf * fmaxf(temp - Tbm, 0.0f));
        snow -= melt;
        cum = (snow < NZ) ? NZ : (cum + melt);
        liq += melt;
        const float overflow = fmaxf(liq - swi * snow, 0.0f);
        liq -= overflow;
        const float wavail = rain + overflow;

        // --- infiltration (6-way softmax blend) ---
        float sat1 = clip01(sw1 * inv_msw1);
        const float dry1 = clip01(1.0f - sat1);
        const float e0 = __expf(wc0.x), e1 = __expf(wc0.y), e2 = __expf(wc0.z),
                    e3 = __expf(wc0.w), e4 = __expf(wc1.x), e5 = __expf(wc1.y);
        const float rsi = 1.0f / (e0 + e1 + e2 + e3 + e4 + e5);
        const float p1 = __powf(sat1, hbv_beta);
        const float p2 = __powf(dry1, vic_bexp);
        const float infil = wavail * rsi *
            (e0 * inf_pc + e1 * (1.0f - p1) + e2 * p2 +
             e3 * (hmets_al * dry1) + e4 * (1.0f - sat1 * sat1) + e5);

        sw1 += infil;
        const float excess = fmaxf(sw1 - msw1, 0.0f);
        sw1 -= excess;
        const float surf = wavail - infil + excess;

        // --- percolation ---
        sat1 = clip01(sw1 * inv_msw1);
        const float perc = fminf(g0 * perc_fac * fmaxf(sat1 - sfc, 0.0f), sw1);
        sw1 -= perc; sw2 += perc;

        // --- capillary rise ---
        float sat2 = clip01(sw2 * inv_msw2);
        sat1 = clip01(sw1 * inv_msw1);
        const float capi = fminf(g1 * crise * (1.0f - sat1) * sat2, sw2);
        sw2 -= capi; sw1 += capi;

        // --- ET ---
        sat1 = clip01(sw1 * inv_msw1);
        const float et = fminf(pet * sat1, sw1);
        sw1 -= et;

        // --- baseflow 1 (6-way softmax blend) ---
        sat1 = clip01(sw1 * inv_msw1);
        const float f0 = __expf(wc1.z), f1 = __expf(wc1.w), f2 = __expf(wc2.x),
                    f3 = __expf(wc2.y), f4 = __expf(wc2.z), f5 = __expf(wc2.w);
        const float rb1 = 1.0f / (f0 + f1 + f2 + f3 + f4 + f5);
        const float q = sw1 * inv_x3_1;
        const float q4 = (q * q) * (q * q);
        const float gr1 = sw1 * (1.0f - __powf(1.0f + q4, -0.25f));
        const float pw1 = __powf(sat1, bfn1);
        const float ex1 = __expf(lam * sat1) - 1.0f;
        const float bsum1 = f0 * gr1 + f1 * (pow10_1 * sw1) + f2 * (bfmax1 * pw1) +
                            f3 * (bfmax1 * sat1) + f4 * (b1o4 * ex1) +
                            f5 * (b1o5 * fmaxf(sat1 - th1, 0.0f));
        const float bf1 = fminf(bsum1 * rb1, sw1);
        sw1 -= bf1;

        // --- baseflow 2 (6-way softmax blend) ---
        sat2 = clip01(sw2 * inv_msw2);
        const float c0 = __expf(wc3.x), c1 = __expf(wc3.y), c2 = __expf(wc3.z),
                    c3 = __expf(wc3.w), c4 = __expf(wc4.x), c5 = __expf(wc4.y);
        const float rb2 = 1.0f / (c0 + c1 + c2 + c3 + c4 + c5);
        const float u = sw2 * inv_x3_2;
        const float u4 = (u * u) * (u * u);
        const float gr2 = sw2 * (1.0f - __powf(1.0f + u4, -0.25f));
        const float pw2 = __powf(sat2, bfn2);
        const float t10 = pow10_2 * sw2;
        const float bsum2 = c0 * gr2 + c1 * t10 + c2 * (bfmax2 * pw2) +
                            c3 * (bfmax2 * sat2) + c4 * (bfmax2 * sat2 * sat2) +
                            c5 * (t10 * sat2);
        const float bf2 = fminf(bsum2 * rb2, sw2);
        sw2 -= bf2;

        // --- outputs ---
        const size_t o = (size_t)t * N_GRID + g;
        surf_o[o] = surf;
        base_o[o] = bf1 + bf2;
        gate_o[o] = (unsigned char)((g4 > 0.5f ? 1 : 0) | (g5 > 0.5f ? 2 : 0));

        // rotate prefetched inputs
        xc0 = xn0; xc1 = xn1; xc2 = xn2;
        wc0 = wn0; wc1 = wn1; wc2 = wn2; wc3 = wn3; wc4 = wn4; wc5 = wn5;
    }
}

// ---------------------------------------------------------------------------
// Kernel 3: unit-hydrograph routing + gate blend.  Fully parallel over (t,g).
// ---------------------------------------------------------------------------
__global__ __launch_bounds__(256)
void route_kernel(const float* __restrict__ surf,
                  const float* __restrict__ base,
                  const float* __restrict__ uh1,
                  const float* __restrict__ uh2,
                  const unsigned char* __restrict__ gates,
                  float* __restrict__ out)
{
    const int g = blockIdx.x * 256 + threadIdx.x;
    if (g >= N_GRID) return;
    const int t = blockIdx.y;
    const size_t o = (size_t)t * N_GRID + g;

    const unsigned char gb = gates[o];
    const float s0 = surf[o];
    const float b0 = base[o];

    float accs = 0.0f, accb = 0.0f;
    #pragma unroll
    for (int lag = 0; lag < UH_LEN; ++lag) {
        const int tt = t - lag;
        const float sv = (tt >= 0) ? surf[(size_t)tt * N_GRID + g] : 0.0f;
        const float bv = (tt >= 0) ? base[(size_t)tt * N_GRID + g] : 0.0f;
        accs += uh1[lag * N_GRID + g] * sv;
        accb += uh2[lag * N_GRID + g] * bv;
    }
    const float qs = (gb & 1) ? accs : s0;
    const float qb = (gb & 2) ? accb : b0;
    out[o] = qs + qb;
}

// ---------------------------------------------------------------------------
extern "C" void kernel_launch(void* const* d_in, const int* in_sizes, int n_in,
                              void* d_out, int out_size, void* d_ws, size_t ws_size,
                              hipStream_t stream)
{
    const float* x_phy = (const float*)d_in[0];   // (T, G, 3)
    const float* wts   = (const float*)d_in[1];   // (T, G, 24)
    const float* hyb   = (const float*)d_in[2];   // (G, 32)
    float* out = (float*)d_out;                   // (T, G)

    // workspace layout (needs ~26.5 MB)
    const size_t TG = (size_t)T_STEPS * N_GRID;
    float* surf = (float*)d_ws;
    float* base = surf + TG;
    float* uh1  = base + TG;
    float* uh2  = uh1 + (size_t)UH_LEN * N_GRID;
    unsigned char* gbits = (unsigned char*)(uh2 + (size_t)UH_LEN * N_GRID);

    uh_kernel<<<dim3((N_GRID + 255) / 256), dim3(256), 0, stream>>>(hyb, uh1, uh2);
    scan_kernel<<<dim3((N_GRID + 63) / 64), dim3(64), 0, stream>>>(
        x_phy, wts, hyb, surf, base, gbits);
    route_kernel<<<dim3((N_GRID + 255) / 256, T_STEPS), dim3(256), 0, stream>>>(
        surf, base, uh1, uh2, gbits, out);
}